// Round 3
// baseline (7219.532 us; speedup 1.0000x reference)
//
#include <hip/hip_runtime.h>

// DefSeq R3: persistent recurrence kernel with MANUAL grid barrier (plain launch;
// R2's hipLaunchCooperativeKernel silently failed -> hs_b stayed poisoned).
// + global_load_lds bf16 GEMM for the vocab projection.

typedef __bf16 bf16;
typedef __bf16 bf16x8 __attribute__((ext_vector_type(8)));
typedef __bf16 bf16x4v __attribute__((ext_vector_type(4)));
typedef float f32x4 __attribute__((ext_vector_type(4)));

#define Vv 32000
#define Ee 512
#define Hh 1024
#define Ss 32
#define Bb 32
#define KC 1536  // E + H
#define NBLK 256 // persistent grid: 256 blocks <= 256 CUs x >=1 block/CU => co-resident

static __device__ __forceinline__ float sigf(float x) { return 1.0f / (1.0f + __expf(-x)); }

__device__ __forceinline__ void gll16(const void* g, void* l) {
  __builtin_amdgcn_global_load_lds((const __attribute__((address_space(1))) unsigned int*)g,
                                   (__attribute__((address_space(3))) unsigned int*)l, 16, 0, 0);
}

// sense-reversal grid barrier (device-scope atomics; same lowering as cg grid.sync)
__device__ __forceinline__ void gbar(unsigned* cnt, unsigned* gen, int tid) {
  __syncthreads();  // drains vmcnt: all block stores committed before arrive
  if (tid == 0) {
    __threadfence();
    unsigned g = __hip_atomic_load(gen, __ATOMIC_RELAXED, __HIP_MEMORY_SCOPE_AGENT);
    unsigned a = __hip_atomic_fetch_add(cnt, 1u, __ATOMIC_ACQ_REL, __HIP_MEMORY_SCOPE_AGENT);
    if (a == NBLK - 1) {
      __hip_atomic_store(cnt, 0u, __ATOMIC_RELAXED, __HIP_MEMORY_SCOPE_AGENT);
      __hip_atomic_fetch_add(gen, 1u, __ATOMIC_RELEASE, __HIP_MEMORY_SCOPE_AGENT);
    } else {
      while (__hip_atomic_load(gen, __ATOMIC_ACQUIRE, __HIP_MEMORY_SCOPE_AGENT) == g)
        __builtin_amdgcn_s_sleep(2);
    }
    __threadfence();
  }
  __syncthreads();
}

// ---------------- consolidated setup: weight conversions + gathers ----------------

#define NG  (4096 * 1536)
#define NZR (1536 * 1536)
#define NWH (1024 * 1536)
#define NWO4 (32000 * 1024 / 4)
#define NSE (Ss * Bb * Ee)
#define NWE (Bb * Ee)

__global__ void k_setup(const float* __restrict__ Wih, const float* __restrict__ Whh,
                        const float* __restrict__ Wz, const float* __restrict__ Wr,
                        const float* __restrict__ Whm, const float* __restrict__ Wo,
                        const int* __restrict__ word, const int* __restrict__ seq,
                        const float* __restrict__ emb,
                        bf16* __restrict__ Wg_h, bf16* __restrict__ Wg_l,
                        bf16* __restrict__ Wzr_h, bf16* __restrict__ Wzr_l,
                        bf16* __restrict__ Wh_h, bf16* __restrict__ Wh_l,
                        bf16* __restrict__ Wo_b,
                        bf16* __restrict__ se_h, bf16* __restrict__ se_l,
                        float* __restrict__ we, bf16* __restrict__ x2h, bf16* __restrict__ x2l,
                        unsigned* __restrict__ bar, int useWo) {
  int T = gridDim.x * blockDim.x;
  int t0 = blockIdx.x * blockDim.x + threadIdx.x;
  if (t0 == 0) { bar[0] = 0u; bar[1] = 0u; }  // barrier cnt/gen (ws is re-poisoned each call)
  // Wg = [Wih | Whh], hi/lo split
  for (int i = t0; i < NG; i += T) {
    int j = i / KC, k = i - j * KC;
    float v = (k < Ee) ? Wih[(size_t)j * Ee + k] : Whh[(size_t)j * Hh + (k - Ee)];
    bf16 h = (bf16)v;
    Wg_h[i] = h;
    Wg_l[i] = (bf16)(v - (float)h);
  }
  // Wzr rows [0,1024)=Wz, [1024,1536)=Wr
  for (int i = t0; i < NZR; i += T) {
    int j = i / KC, k = i - j * KC;
    float v = (j < Hh) ? Wz[(size_t)j * KC + k] : Wr[(size_t)(j - Hh) * KC + k];
    bf16 h = (bf16)v;
    Wzr_h[i] = h;
    Wzr_l[i] = (bf16)(v - (float)h);
  }
  // Wh
  for (int i = t0; i < NWH; i += T) {
    float v = Whm[i];
    bf16 h = (bf16)v;
    Wh_h[i] = h;
    Wh_l[i] = (bf16)(v - (float)h);
  }
  // Wo -> bf16 (single term; error budget allows)
  if (useWo) {
    for (int i = t0; i < NWO4; i += T) {
      float4 v = ((const float4*)Wo)[i];
      bf16x4v b4 = {(bf16)v.x, (bf16)v.y, (bf16)v.z, (bf16)v.w};
      *(bf16x4v*)&Wo_b[(size_t)i * 4] = b4;
    }
  }
  // seq embedding gather, hi/lo
  for (int i = t0; i < NSE; i += T) {
    int tb = i >> 9, e = i & 511;
    float v = emb[(size_t)seq[tb] * Ee + e];
    bf16 h = (bf16)v;
    se_h[i] = h;
    se_l[i] = (bf16)(v - (float)h);
  }
  // we gather + x2 left half init
  for (int i = t0; i < NWE; i += T) {
    int b = i >> 9, e = i & 511;
    float v = emb[(size_t)word[b] * Ee + e];
    we[i] = v;
    bf16 h = (bf16)v;
    x2h[(size_t)b * KC + e] = h;
    x2l[(size_t)b * KC + e] = (bf16)(v - (float)h);
  }
}

// h0 = we @ Wl.T + bl ; c = h0 ; hp = bf16split(h0)
__global__ void k_init_h0(const float* __restrict__ we, const float* __restrict__ Wl,
                          const float* __restrict__ bl, float* __restrict__ c,
                          bf16* __restrict__ hp_h, bf16* __restrict__ hp_l) {
  int o = blockIdx.x * 4 + (threadIdx.x >> 6);
  int lane = threadIdx.x & 63;
  int b = o >> 10, n = o & 1023;
  const float* wr = we + b * Ee;
  const float* wl = Wl + (size_t)n * Ee;
  int e0 = lane * 8;
  float4 a0 = *(const float4*)(wr + e0);
  float4 a1 = *(const float4*)(wr + e0 + 4);
  float4 b0 = *(const float4*)(wl + e0);
  float4 b1 = *(const float4*)(wl + e0 + 4);
  float s = a0.x * b0.x + a0.y * b0.y + a0.z * b0.z + a0.w * b0.w +
            a1.x * b1.x + a1.y * b1.y + a1.z * b1.z + a1.w * b1.w;
  for (int off = 32; off; off >>= 1) s += __shfl_down(s, off);
  if (lane == 0) {
    s += bl[n];
    c[o] = s;
    bf16 h = (bf16)s;
    hp_h[o] = h;
    hp_l[o] = (bf16)(s - (float)h);
  }
}

// ---------------- persistent recurrence ----------------

struct CoopArgs {
  const bf16 *se_h, *se_l;
  bf16 *hp_h, *hp_l;
  const bf16 *Wg_h, *Wg_l, *Wzr_h, *Wzr_l, *Wh_h, *Wh_l;
  const float *bih, *bhh, *bz, *br, *bh;
  const float* we;
  float *c, *hl, *z, *h;
  bf16 *x2h, *x2l, *x3h, *x3l, *hs_b;
  unsigned* bar;
};

__global__ __launch_bounds__(256) void k_recur(CoopArgs a) {
  int bid = blockIdx.x;
  int tid = threadIdx.x;
  int w = tid >> 6, lane = tid & 63;
  int l16 = lane & 15, quad = lane >> 4;
  unsigned* bcnt = a.bar;
  unsigned* bgen = a.bar + 1;
  __shared__ float red[4][Bb][16];

  for (int t = 0; t < Ss; ++t) {
    // ===== phase A (all 256 blocks): gates GEMM + LSTM pointwise =====
    {
      int kbase = bid * 4;
      // B-frag row for lane l16: j = gate(l16>>2)*1024 + kbase + (l16&3)
      size_t woff = ((size_t)((l16 >> 2) << 10) + kbase + (l16 & 3)) * KC;
      const bf16* se_th = a.se_h + (size_t)t * Bb * Ee;
      const bf16* se_tl = a.se_l + (size_t)t * Bb * Ee;
      f32x4 acc[2][3];
#pragma unroll
      for (int mt = 0; mt < 2; ++mt)
#pragma unroll
        for (int q = 0; q < 3; ++q) acc[mt][q] = (f32x4){0.f, 0.f, 0.f, 0.f};
      int kk0 = w * (KC / 4), kk1 = kk0 + (KC / 4);
      for (int kk = kk0; kk < kk1; kk += 32) {
        bf16x8 bh_ = *(const bf16x8*)(a.Wg_h + woff + kk + quad * 8);
        bf16x8 bl_ = *(const bf16x8*)(a.Wg_l + woff + kk + quad * 8);
#pragma unroll
        for (int mt = 0; mt < 2; ++mt) {
          int b = mt * 16 + l16;
          const bf16 *pah, *pal;
          if (kk < Ee) {
            pah = se_th + (size_t)b * Ee + kk;
            pal = se_tl + (size_t)b * Ee + kk;
          } else {
            pah = a.hp_h + (size_t)b * Hh + (kk - Ee);
            pal = a.hp_l + (size_t)b * Hh + (kk - Ee);
          }
          bf16x8 ah = *(const bf16x8*)(pah + quad * 8);
          bf16x8 al = *(const bf16x8*)(pal + quad * 8);
          acc[mt][0] = __builtin_amdgcn_mfma_f32_16x16x32_bf16(ah, bh_, acc[mt][0], 0, 0, 0);
          acc[mt][1] = __builtin_amdgcn_mfma_f32_16x16x32_bf16(al, bh_, acc[mt][1], 0, 0, 0);
          acc[mt][2] = __builtin_amdgcn_mfma_f32_16x16x32_bf16(ah, bl_, acc[mt][2], 0, 0, 0);
        }
      }
#pragma unroll
      for (int mt = 0; mt < 2; ++mt)
#pragma unroll
        for (int r = 0; r < 4; ++r)
          red[w][mt * 16 + quad * 4 + r][l16] = acc[mt][0][r] + acc[mt][1][r] + acc[mt][2][r];
      __syncthreads();
      if (tid < 128) {
        int b = tid >> 2, cc = tid & 3;
        int kg = kbase + cc;
        float g4[4];
#pragma unroll
        for (int g = 0; g < 4; ++g) {
          float v = 0.f;
#pragma unroll
          for (int w2 = 0; w2 < 4; ++w2) v += red[w2][b][g * 4 + cc];
          int j = g * Hh + kg;
          g4[g] = v + a.bih[j] + a.bhh[j];
        }
        float co = a.c[b * Hh + kg];
        float cn = sigf(g4[1]) * co + sigf(g4[0]) * tanhf(g4[2]);
        float hlv = sigf(g4[3]) * tanhf(cn);
        a.c[b * Hh + kg] = cn;
        a.hl[b * Hh + kg] = hlv;
        bf16 hb = (bf16)hlv;
        bf16 lb = (bf16)(hlv - (float)hb);
        a.x2h[(size_t)b * KC + Ee + kg] = hb;
        a.x2l[(size_t)b * KC + Ee + kg] = lb;
        a.x3h[(size_t)b * KC + Ee + kg] = hb;
        a.x3l[(size_t)b * KC + Ee + kg] = lb;
      }
    }
    gbar(bcnt, bgen, tid);

    // ===== phase B (blocks < 96): [z;r] GEMM + epilogue =====
    if (bid < 96) {
      int j0 = bid * 16;
      size_t woff = (size_t)(j0 + l16) * KC;
      f32x4 acc[2][3];
#pragma unroll
      for (int mt = 0; mt < 2; ++mt)
#pragma unroll
        for (int q = 0; q < 3; ++q) acc[mt][q] = (f32x4){0.f, 0.f, 0.f, 0.f};
      int kk0 = w * (KC / 4), kk1 = kk0 + (KC / 4);
      for (int kk = kk0; kk < kk1; kk += 32) {
        bf16x8 bh_ = *(const bf16x8*)(a.Wzr_h + woff + kk + quad * 8);
        bf16x8 bl_ = *(const bf16x8*)(a.Wzr_l + woff + kk + quad * 8);
#pragma unroll
        for (int mt = 0; mt < 2; ++mt) {
          int b = mt * 16 + l16;
          bf16x8 ah = *(const bf16x8*)(a.x2h + (size_t)b * KC + kk + quad * 8);
          bf16x8 al = *(const bf16x8*)(a.x2l + (size_t)b * KC + kk + quad * 8);
          acc[mt][0] = __builtin_amdgcn_mfma_f32_16x16x32_bf16(ah, bh_, acc[mt][0], 0, 0, 0);
          acc[mt][1] = __builtin_amdgcn_mfma_f32_16x16x32_bf16(al, bh_, acc[mt][1], 0, 0, 0);
          acc[mt][2] = __builtin_amdgcn_mfma_f32_16x16x32_bf16(ah, bl_, acc[mt][2], 0, 0, 0);
        }
      }
#pragma unroll
      for (int mt = 0; mt < 2; ++mt)
#pragma unroll
        for (int r = 0; r < 4; ++r)
          red[w][mt * 16 + quad * 4 + r][l16] = acc[mt][0][r] + acc[mt][1][r] + acc[mt][2][r];
      __syncthreads();
#pragma unroll
      for (int i = 0; i < 2; ++i) {
        int idx = tid + i * 256;
        int b = idx >> 4, nl = idx & 15;
        int j = j0 + nl;
        float v = red[0][b][nl] + red[1][b][nl] + red[2][b][nl] + red[3][b][nl];
        if (j < Hh) {
          a.z[b * Hh + j] = sigf(v + a.bz[j]);
        } else {
          int e = j - Hh;
          float rv = sigf(v + a.br[e]) * a.we[b * Ee + e];
          bf16 hb = (bf16)rv;
          a.x3h[(size_t)b * KC + e] = hb;
          a.x3l[(size_t)b * KC + e] = (bf16)(rv - (float)hb);
        }
      }
    }
    gbar(bcnt, bgen, tid);

    // ===== phase C (blocks < 64): hh GEMM + h combine =====
    if (bid < 64) {
      int j0 = bid * 16;
      size_t woff = (size_t)(j0 + l16) * KC;
      f32x4 acc[2][3];
#pragma unroll
      for (int mt = 0; mt < 2; ++mt)
#pragma unroll
        for (int q = 0; q < 3; ++q) acc[mt][q] = (f32x4){0.f, 0.f, 0.f, 0.f};
      int kk0 = w * (KC / 4), kk1 = kk0 + (KC / 4);
      for (int kk = kk0; kk < kk1; kk += 32) {
        bf16x8 bh_ = *(const bf16x8*)(a.Wh_h + woff + kk + quad * 8);
        bf16x8 bl_ = *(const bf16x8*)(a.Wh_l + woff + kk + quad * 8);
#pragma unroll
        for (int mt = 0; mt < 2; ++mt) {
          int b = mt * 16 + l16;
          bf16x8 ah = *(const bf16x8*)(a.x3h + (size_t)b * KC + kk + quad * 8);
          bf16x8 al = *(const bf16x8*)(a.x3l + (size_t)b * KC + kk + quad * 8);
          acc[mt][0] = __builtin_amdgcn_mfma_f32_16x16x32_bf16(ah, bh_, acc[mt][0], 0, 0, 0);
          acc[mt][1] = __builtin_amdgcn_mfma_f32_16x16x32_bf16(al, bh_, acc[mt][1], 0, 0, 0);
          acc[mt][2] = __builtin_amdgcn_mfma_f32_16x16x32_bf16(ah, bl_, acc[mt][2], 0, 0, 0);
        }
      }
#pragma unroll
      for (int mt = 0; mt < 2; ++mt)
#pragma unroll
        for (int r = 0; r < 4; ++r)
          red[w][mt * 16 + quad * 4 + r][l16] = acc[mt][0][r] + acc[mt][1][r] + acc[mt][2][r];
      __syncthreads();
#pragma unroll
      for (int i = 0; i < 2; ++i) {
        int idx = tid + i * 256;
        int b = idx >> 4, nl = idx & 15;
        int j = j0 + nl;
        float v = red[0][b][nl] + red[1][b][nl] + red[2][b][nl] + red[3][b][nl];
        float hhv = tanhf(v + a.bh[j]);
        float hlv = a.hl[b * Hh + j];
        float zz = a.z[b * Hh + j];
        float hn = (1.f - zz) * hlv + zz * hhv;
        a.h[b * Hh + j] = hn;
        bf16 hb = (bf16)hn;
        a.hp_h[b * Hh + j] = hb;
        a.hp_l[b * Hh + j] = (bf16)(hn - (float)hb);
        a.hs_b[((size_t)t * Bb + b) * Hh + j] = hb;
      }
    }
    gbar(bcnt, bgen, tid);
  }
}

// ---------------- vocab projection ----------------

// m97-style: bf16 A and B staged via global_load_lds width-16.
__global__ __launch_bounds__(256) void k_gemm2(const bf16* __restrict__ hs,
                                               const bf16* __restrict__ Wob,
                                               const float* __restrict__ bo,
                                               float* __restrict__ out) {
  int id = blockIdx.x;
  int r_ = id & 7, s_ = id >> 3;
  int mi = s_ & 7;
  int ni = (s_ >> 3) * 8 + r_;
  if (ni >= Vv / 128) return;
  int m0 = mi * 128, n0 = ni * 128;

  int tid = threadIdx.x;
  int w = tid >> 6, lane = tid & 63;
  int l16 = lane & 15, quad = lane >> 4;
  int wm = w & 1, wn = w >> 1;
  int row_in = lane >> 2, cch = lane & 3;

  __shared__ bf16 A_lds[128 * 32];
  __shared__ bf16 B_lds[128 * 32];

  f32x4 acc[4][4];
#pragma unroll
  for (int i = 0; i < 4; ++i)
#pragma unroll
    for (int j = 0; j < 4; ++j) acc[i][j] = (f32x4){0.f, 0.f, 0.f, 0.f};

  for (int kt = 0; kt < 32; ++kt) {
    int k0 = kt * 32;
#pragma unroll
    for (int i = 0; i < 2; ++i) {
      int rbase = w * 32 + i * 16;
      int rowA = rbase + row_in;
      gll16(hs + (size_t)(m0 + rowA) * Hh + k0 + cch * 8, &A_lds[rbase * 32]);
      gll16(Wob + (size_t)(n0 + rowA) * Hh + k0 + cch * 8, &B_lds[rbase * 32]);
    }
    __syncthreads();

    const bf16* Ab = &A_lds[(wm * 64 + l16) * 32 + quad * 8];
    const bf16* Bx = &B_lds[(wn * 64 + l16) * 32 + quad * 8];
    bf16x8 af[4], bfr[4];
#pragma unroll
    for (int i = 0; i < 4; ++i) af[i] = *(const bf16x8*)(Ab + i * 16 * 32);
#pragma unroll
    for (int j = 0; j < 4; ++j) bfr[j] = *(const bf16x8*)(Bx + j * 16 * 32);
#pragma unroll
    for (int i = 0; i < 4; ++i)
#pragma unroll
      for (int j = 0; j < 4; ++j)
        acc[i][j] = __builtin_amdgcn_mfma_f32_16x16x32_bf16(af[i], bfr[j], acc[i][j], 0, 0, 0);
    __syncthreads();
  }

#pragma unroll
  for (int i = 0; i < 4; ++i)
#pragma unroll
    for (int j = 0; j < 4; ++j)
#pragma unroll
      for (int r = 0; r < 4; ++r) {
        int m = m0 + wm * 64 + i * 16 + quad * 4 + r;
        int n = n0 + wn * 64 + j * 16 + l16;
        out[(size_t)m * Vv + n] = acc[i][j][r] + bo[n];
      }
}

// fallback (R1-proven): reads fp32 Wo directly, converts in-kernel
__global__ __launch_bounds__(256) void k_gemm_out(const bf16* __restrict__ hs,
                                                  const float* __restrict__ Wo,
                                                  const float* __restrict__ bo,
                                                  float* __restrict__ out) {
  int id = blockIdx.x;
  int r_ = id & 7, s_ = id >> 3;
  int mi = s_ & 7;
  int ni = (s_ >> 3) * 8 + r_;
  if (ni >= Vv / 128) return;
  int m0 = mi * 128, n0 = ni * 128;
  int tid = threadIdx.x;
  int w = tid >> 6, lane = tid & 63;
  int l16 = lane & 15, quad = lane >> 4;
  int wm = w & 1, wn = w >> 1;
  __shared__ bf16 A_lds[128 * 32];
  __shared__ bf16 B_lds[128 * 32];
  f32x4 acc[4][4];
#pragma unroll
  for (int i = 0; i < 4; ++i)
#pragma unroll
    for (int j = 0; j < 4; ++j) acc[i][j] = (f32x4){0.f, 0.f, 0.f, 0.f};
  for (int kt = 0; kt < 32; ++kt) {
    int k0 = kt * 32;
#pragma unroll
    for (int i = 0; i < 2; ++i) {
      int cid = tid + i * 256;
      int row = cid >> 2, ch = cid & 3;
      *(int4*)&A_lds[row * 32 + ch * 8] = *(const int4*)&hs[(size_t)(m0 + row) * Hh + k0 + ch * 8];
    }
#pragma unroll
    for (int i = 0; i < 4; ++i) {
      int cid = tid + i * 256;
      int row = cid >> 3, ch = cid & 7;
      float4 v = *(const float4*)&Wo[(size_t)(n0 + row) * Hh + k0 + ch * 4];
      bf16x4v bv = {(bf16)v.x, (bf16)v.y, (bf16)v.z, (bf16)v.w};
      *(bf16x4v*)&B_lds[row * 32 + ch * 4] = bv;
    }
    __syncthreads();
    const bf16* Ab = &A_lds[(wm * 64 + l16) * 32 + quad * 8];
    const bf16* Bx = &B_lds[(wn * 64 + l16) * 32 + quad * 8];
    bf16x8 af[4], bfr[4];
#pragma unroll
    for (int i = 0; i < 4; ++i) af[i] = *(const bf16x8*)(Ab + i * 16 * 32);
#pragma unroll
    for (int j = 0; j < 4; ++j) bfr[j] = *(const bf16x8*)(Bx + j * 16 * 32);
#pragma unroll
    for (int i = 0; i < 4; ++i)
#pragma unroll
      for (int j = 0; j < 4; ++j)
        acc[i][j] = __builtin_amdgcn_mfma_f32_16x16x32_bf16(af[i], bfr[j], acc[i][j], 0, 0, 0);
    __syncthreads();
  }
#pragma unroll
  for (int i = 0; i < 4; ++i)
#pragma unroll
    for (int j = 0; j < 4; ++j)
#pragma unroll
      for (int r = 0; r < 4; ++r) {
        int m = m0 + wm * 64 + i * 16 + quad * 4 + r;
        int n = n0 + wn * 64 + j * 16 + l16;
        out[(size_t)m * Vv + n] = acc[i][j][r] + bo[n];
      }
}

__global__ void k_copy_hc(const float* __restrict__ h_f32, const float* __restrict__ c_f32,
                          float* __restrict__ out) {
  int i = blockIdx.x * 256 + threadIdx.x;
  size_t base = (size_t)Ss * Bb * Vv;
  out[base + i] = h_f32[i];
  out[base + Bb * Hh + i] = c_f32[i];
}

// ---------------- host ----------------

extern "C" void kernel_launch(void* const* d_in, const int* in_sizes, int n_in,
                              void* d_out, int out_size, void* d_ws, size_t ws_size,
                              hipStream_t stream) {
  const int* word = (const int*)d_in[0];
  const int* seq = (const int*)d_in[1];
  const float* emb = (const float*)d_in[2];
  const float* Wl = (const float*)d_in[3];
  const float* bl = (const float*)d_in[4];
  const float* Wih = (const float*)d_in[5];
  const float* Whh = (const float*)d_in[6];
  const float* bih = (const float*)d_in[7];
  const float* bhh = (const float*)d_in[8];
  const float* Wz = (const float*)d_in[9];
  const float* bz = (const float*)d_in[10];
  const float* Wr = (const float*)d_in[11];
  const float* br = (const float*)d_in[12];
  const float* Wh = (const float*)d_in[13];
  const float* bh = (const float*)d_in[14];
  const float* Wo = (const float*)d_in[15];
  const float* bo = (const float*)d_in[16];
  float* out = (float*)d_out;

  char* p = (char*)d_ws;
  auto alloc = [&](size_t bytes) -> char* {
    char* q = p;
    p += (bytes + 255) & ~(size_t)255;
    return q;
  };
  unsigned* bar = (unsigned*)alloc(256);
  float* we_f32 = (float*)alloc(Bb * Ee * 4);
  bf16* hp_h = (bf16*)alloc(Bb * Hh * 2);
  bf16* hp_l = (bf16*)alloc(Bb * Hh * 2);
  float* hl_f32 = (float*)alloc(Bb * Hh * 4);
  float* c_f32 = (float*)alloc(Bb * Hh * 4);
  float* z_f32 = (float*)alloc(Bb * Hh * 4);
  float* h_f32 = (float*)alloc(Bb * Hh * 4);
  bf16* x2h = (bf16*)alloc(Bb * KC * 2);
  bf16* x2l = (bf16*)alloc(Bb * KC * 2);
  bf16* x3h = (bf16*)alloc(Bb * KC * 2);
  bf16* x3l = (bf16*)alloc(Bb * KC * 2);
  bf16* se_h = (bf16*)alloc((size_t)Ss * Bb * Ee * 2);
  bf16* se_l = (bf16*)alloc((size_t)Ss * Bb * Ee * 2);
  bf16* hs_b = (bf16*)alloc((size_t)Ss * Bb * Hh * 2);
  bf16* Wg_h = (bf16*)alloc((size_t)4 * Hh * KC * 2);
  bf16* Wg_l = (bf16*)alloc((size_t)4 * Hh * KC * 2);
  bf16* Wzr_h = (bf16*)alloc((size_t)KC * KC * 2);
  bf16* Wzr_l = (bf16*)alloc((size_t)KC * KC * 2);
  bf16* Wh_h = (bf16*)alloc((size_t)Hh * KC * 2);
  bf16* Wh_l = (bf16*)alloc((size_t)Hh * KC * 2);
  size_t used_before_wo = (size_t)(p - (char*)d_ws);
  size_t wo_bytes = (size_t)Vv * Hh * 2;
  int useWo = (used_before_wo + wo_bytes + 256 <= ws_size) ? 1 : 0;
  bf16* Wo_b = useWo ? (bf16*)alloc(wo_bytes) : (bf16*)Wg_h /*unused*/;

  dim3 blk(256);
  k_setup<<<2048, blk, 0, stream>>>(Wih, Whh, Wz, Wr, Wh, Wo, word, seq, emb, Wg_h, Wg_l,
                                    Wzr_h, Wzr_l, Wh_h, Wh_l, Wo_b, se_h, se_l, we_f32, x2h,
                                    x2l, bar, useWo);
  k_init_h0<<<8192, blk, 0, stream>>>(we_f32, Wl, bl, c_f32, hp_h, hp_l);

  CoopArgs ca;
  ca.se_h = se_h; ca.se_l = se_l;
  ca.hp_h = hp_h; ca.hp_l = hp_l;
  ca.Wg_h = Wg_h; ca.Wg_l = Wg_l;
  ca.Wzr_h = Wzr_h; ca.Wzr_l = Wzr_l;
  ca.Wh_h = Wh_h; ca.Wh_l = Wh_l;
  ca.bih = bih; ca.bhh = bhh; ca.bz = bz; ca.br = br; ca.bh = bh;
  ca.we = we_f32;
  ca.c = c_f32; ca.hl = hl_f32; ca.z = z_f32; ca.h = h_f32;
  ca.x2h = x2h; ca.x2l = x2l; ca.x3h = x3h; ca.x3l = x3l; ca.hs_b = hs_b;
  ca.bar = bar;
  k_recur<<<NBLK, blk, 0, stream>>>(ca);

  if (useWo)
    k_gemm2<<<2048, blk, 0, stream>>>(hs_b, Wo_b, bo, out);
  else
    k_gemm_out<<<2048, blk, 0, stream>>>(hs_b, Wo, bo, out);
  k_copy_hc<<<128, blk, 0, stream>>>(h_f32, c_f32, out);
}